// Round 10
// baseline (372.764 us; speedup 1.0000x reference)
//
#include <hip/hip_runtime.h>

#define INCH 128
#define C1   16
#define C2   64
#define LOCB 7                   // log2(nodes per bucket)
#define BNODES (1 << LOCB)       // 128 nodes per bucket
#define CAP  8192                // padded edge capacity per bucket
#define ROWBITS 17
#define ROWMASK ((1 << ROWBITS) - 1)
#define SENT 0xFFFFFFFFu         // sentinel: src field = 0x1FFFF >= n -> filtered
#define ACC2P 9                  // u64 acc row stride (odd -> bank-pair spread)
#define FXS   16384.0f           // 2^14 fixed-point scale
#define INVFX 6.103515625e-05f   // 2^-14
#define FXBH  524288.5f          // 2^19 bias + 0.5 (round-half-up via trunc)
#define BSH   19                 // bias shift for de-biasing
#define BKT_T 1024               // bucket_kernel threads
#define AGG_T 512                // agg threads

typedef int iv4 __attribute__((ext_vector_type(4)));
typedef unsigned long long ulv2 __attribute__((ext_vector_type(2)));

// ---------------- binit: gcur[b] = b*CAP; deg[] = 0 ------------------------
__global__ void binit_kernel(int* __restrict__ gcur, int K,
                             int* __restrict__ deg, int n) {
    int t = blockIdx.x * blockDim.x + threadIdx.x;
    if (t < K) gcur[t] = t * CAP;
    if (t < n) deg[t] = 0;
}

// ---------------- bucket edges + fused global degree histogram -------------
// Verified structure (r2/r4/r7); r9: pass A also counts per-node in-degree
// via no-return global atomics (same loads, pipelined) -> degree_kernel gone.
__global__ __launch_bounds__(BKT_T) void bucket_kernel(
    const int* __restrict__ row, const int* __restrict__ col,
    int* __restrict__ gcur, int* __restrict__ barr, int* __restrict__ deg,
    int e, int n, int K, int nblocks)
{
    __shared__ int cnt[1024];     // valid count per bucket
    __shared__ int cur[1024];     // write cursor
    __shared__ int sst[1024];     // chunk start
    int tid = threadIdx.x;
    int e4 = e >> 2;
    long b0 = (long)blockIdx.x * e4 / nblocks;
    long b1 = (long)(blockIdx.x + 1) * e4 / nblocks;
    const iv4* c4p = (const iv4*)col;
    const iv4* r4p = (const iv4*)row;
    cnt[tid] = 0;
    __syncthreads();
    for (long i = b0 + tid; i < b1; i += BKT_T) {
        iv4 c4 = c4p[i], r4 = r4p[i];
        #pragma unroll
        for (int k = 0; k < 4; ++k) {
            unsigned c = (unsigned)c4[k], r = (unsigned)r4[k];
            if (c < (unsigned)n && r < (unsigned)n) {
                atomicAdd(&cnt[c >> LOCB], 1);
                atomicAdd(&deg[c], 1);              // global, no-return
            }
        }
    }
    if (blockIdx.x == 0) {
        for (int i = e4 * 4 + tid; i < e; i += BKT_T) {
            unsigned c = (unsigned)col[i], r = (unsigned)row[i];
            if (c < (unsigned)n && r < (unsigned)n) {
                atomicAdd(&cnt[c >> LOCB], 1);
                atomicAdd(&deg[c], 1);
            }
        }
    }
    __syncthreads();
    if (tid < K) {
        int c = cnt[tid];
        int start = c ? atomicAdd(&gcur[tid], (c + 15) & ~15) : 0;
        cur[tid] = start;
        sst[tid] = start;
    }
    __syncthreads();
    for (long i = b0 + tid; i < b1; i += BKT_T) {
        iv4 c4 = c4p[i], r4 = r4p[i];
        #pragma unroll
        for (int k = 0; k < 4; ++k) {
            unsigned c = (unsigned)c4[k], r = (unsigned)r4[k];
            if (c < (unsigned)n && r < (unsigned)n) {
                int b = c >> LOCB;
                int slot = atomicAdd(&cur[b], 1);          // LDS int atomic
                if ((unsigned)slot < (unsigned)((b + 1) * CAP))
                    barr[slot] = (int)(r | ((c & (BNODES - 1)) << ROWBITS));
            }
        }
    }
    if (blockIdx.x == 0) {
        for (int i = e4 * 4 + tid; i < e; i += BKT_T) {
            unsigned c = (unsigned)col[i], r = (unsigned)row[i];
            if (c < (unsigned)n && r < (unsigned)n) {
                int b = c >> LOCB;
                int slot = atomicAdd(&cur[b], 1);
                if ((unsigned)slot < (unsigned)((b + 1) * CAP))
                    barr[slot] = (int)(r | ((c & (BNODES - 1)) << ROWBITS));
            }
        }
    }
    __syncthreads();
    // sentinel-fill the pad so every reserved line is fully written
    if (tid < K) {
        int c = cnt[tid];
        if (c) {
            int start = sst[tid];
            int end = start + c;
            int re  = start + ((c + 15) & ~15);
            int lim = (tid + 1) * CAP;
            if (end > lim) end = lim;
            if (re  > lim) re  = lim;
            for (int j = end; j < re; ++j) barr[j] = (int)SENT;
        }
    }
}

// ---------------- linear1: xW1u = u32 fixed-point((x@W1)*inv*2^14 + bias) --
__global__ __launch_bounds__(256) void linear1_kernel(
    const float* __restrict__ x, const float* __restrict__ W1,
    const float* __restrict__ T1, const float* __restrict__ t1b,
    const int* __restrict__ deg,
    unsigned* __restrict__ xW1u, float* __restrict__ xT1, int n)
{
    __shared__ float Wc[INCH][32];        // [:,0:16]=W1, [:,16:32]=t1_W
    __shared__ float xs[16][INCH + 4];
    int tid = threadIdx.x;

    for (int i = tid; i < INCH * C1; i += 256) {
        int k = i / C1, c = i % C1;
        Wc[k][c]      = W1[i];
        Wc[k][c + 16] = T1[i];
    }
    int node0 = blockIdx.x * 16;
    for (int i = tid; i < 16 * (INCH / 4); i += 256) {
        int r = i / (INCH / 4);
        int cc = i % (INCH / 4);
        int node = node0 + r;
        float4 v = make_float4(0.f, 0.f, 0.f, 0.f);
        if (node < n) v = ((const float4*)x)[(size_t)node * (INCH / 4) + cc];
        ((float4*)&xs[r][0])[cc] = v;
    }
    __syncthreads();

    int ch = tid & 15, nl = tid >> 4;
    int node = node0 + nl;
    if (node >= n) return;
    float a1 = 0.f, a2 = 0.f;
    #pragma unroll
    for (int k = 0; k < INCH; ++k) {
        float xv = xs[nl][k];
        a1 += xv * Wc[k][ch];
        a2 += xv * Wc[k][ch + 16];
    }
    float ic = rsqrtf((float)(deg[node] + 1));
    // pre-scaled by inv[src]*2^14, pre-biased by 2^19: atomic-ready integer
    xW1u[(node << 4) + ch] = (unsigned)(a1 * ic * FXS + FXBH);
    xT1[(node << 4) + ch]  = a2 + t1b[ch];
}

// ---- per-edge scatter: values are PRE-PACKED u32 pairs -> load 2x dwordx4
//      as 4 u64 words, feed ds_add_u64 directly. Zero per-edge pack VALU.
#define EDGE_GS(PK, GA, GB)                                                   \
    do {                                                                      \
        if (((PK) & ROWMASK) < un) {                                          \
            unsigned long long* _a = &acc[(((PK) >> ROWBITS) & (BNODES - 1))][tb]; \
            atomicAdd(&_a[0], (GA)[0]);                                       \
            atomicAdd(&_a[1], (GA)[1]);                                       \
            atomicAdd(&_a[2], (GB)[0]);                                       \
            atomicAdd(&_a[3], (GB)[1]);                                       \
        }                                                                     \
    } while (0)

#define GATHER_SCATTER(SRCBUF)                                                \
    {                                                                         \
        int jj = tid >> 1;                                                    \
        for (int i0 = jj * 4; i0 + 3 < len; i0 += (AGG_T * 2)) {              \
            iv4 w = *(const iv4*)(bp + i0);                                   \
            unsigned s0 = (unsigned)w[0] & ROWMASK, s1 = (unsigned)w[1] & ROWMASK; \
            unsigned s2 = (unsigned)w[2] & ROWMASK, s3 = (unsigned)w[3] & ROWMASK; \
            unsigned c0 = s0 < un ? s0 : 0u, c1 = s1 < un ? s1 : 0u;          \
            unsigned c2 = s2 < un ? s2 : 0u, c3 = s3 < un ? s3 : 0u;          \
            const ulv2* p0 = (const ulv2*)(SRCBUF + ((size_t)c0 << 4) + chb); \
            const ulv2* p1 = (const ulv2*)(SRCBUF + ((size_t)c1 << 4) + chb); \
            const ulv2* p2 = (const ulv2*)(SRCBUF + ((size_t)c2 << 4) + chb); \
            const ulv2* p3 = (const ulv2*)(SRCBUF + ((size_t)c3 << 4) + chb); \
            ulv2 ga0 = p0[0], gb0 = p0[1];                                    \
            ulv2 ga1 = p1[0], gb1 = p1[1];                                    \
            ulv2 ga2 = p2[0], gb2 = p2[1];                                    \
            ulv2 ga3 = p3[0], gb3 = p3[1];                                    \
            EDGE_GS((unsigned)w[0], ga0, gb0);                                \
            EDGE_GS((unsigned)w[1], ga1, gb1);                                \
            EDGE_GS((unsigned)w[2], ga2, gb2);                                \
            EDGE_GS((unsigned)w[3], ga3, gb3);                                \
        }                                                                     \
    }

// ---------------- agg1: bucket u64-LDS accumulate + fused epilogue1 --------
__global__ __launch_bounds__(AGG_T) void agg1_bucket_kernel(
    const int* __restrict__ barr, const int* __restrict__ gcur,
    const int* __restrict__ deg, const unsigned* __restrict__ xW1u,
    const float* __restrict__ xT1, const float* __restrict__ b1,
    float* __restrict__ h, unsigned* __restrict__ hu, int n)
{
    __shared__ unsigned long long acc[BNODES][ACC2P];   // 9216 B
    int b = blockIdx.x, tid = threadIdx.x;
    for (int i = tid; i < BNODES * ACC2P; i += AGG_T) (&acc[0][0])[i] = 0ull;
    __syncthreads();

    int base = b * CAP;
    int len = gcur[b] - base;
    if (len < 0) len = 0;
    if (len > CAP) len = CAP;
    const int* bp = barr + base;
    unsigned un = (unsigned)n;
    int chb = (tid & 1) << 3;              // u32 channel base: 0 / 8
    int tb  = (tid & 1) << 2;              // u64 slot base: 0..3 / 4..7

    GATHER_SCATTER(xW1u)
    __syncthreads();

    // epilogue: de-bias (deg+1 biases incl. self), unscale, bias, relu
    const unsigned* au = (const unsigned*)&acc[0][0];
    for (int t = tid; t < BNODES * C1; t += AGG_T) {
        int loc = t >> 4, ch = t & 15;
        int node = (b << LOCB) + loc;
        if (node >= n) continue;
        int idx = (node << 4) + ch;
        int dg = deg[node];
        unsigned wd = au[loc * (2 * ACC2P) + ch];
        int tot = (int)(wd + xW1u[idx] - ((unsigned)(dg + 1) << BSH));
        float ic = rsqrtf((float)(dg + 1));
        float v = (float)tot * INVFX * ic + b1[ch];
        float hv = fmaxf(v, 0.f) + xT1[idx];
        h[idx]  = hv;
        hu[idx] = (unsigned)(hv * ic * FXS + FXBH);  // atomic-ready for layer 2
    }
}

// ---------------- agg2: bucket u64-LDS accumulate + fused 16->64 linears ---
__global__ __launch_bounds__(AGG_T) void agg2_bucket_kernel(
    const int* __restrict__ barr, const int* __restrict__ gcur,
    const int* __restrict__ deg, const unsigned* __restrict__ hu,
    const float* __restrict__ h,
    const float* __restrict__ W2, const float* __restrict__ T2,
    const float* __restrict__ b2, const float* __restrict__ t2b,
    float* __restrict__ out, int n)
{
    __shared__ unsigned long long acc[BNODES][ACC2P];   // 9216 B
    __shared__ float Wc[C1][128];          // 8 KB: [:,0:64]=W2, [:,64:128]=T2
    __shared__ float h_s[BNODES][C1];      // 8 KB: unscaled h for identity2
    __shared__ float accf[BNODES][C1 + 1]; // 8.7 KB: finalized aggregate
    int b = blockIdx.x, tid = threadIdx.x;
    for (int i = tid; i < BNODES * ACC2P; i += AGG_T) (&acc[0][0])[i] = 0ull;
    for (int i = tid; i < C1 * 128; i += AGG_T) {
        int k = i >> 7, c = i & 127;
        Wc[k][c] = (c < 64) ? W2[k * C2 + c] : T2[k * C2 + (c - 64)];
    }
    {   // stage h rows (contiguous across bucket -> coalesced float4)
        int node0 = b << LOCB;
        for (int t = tid; t < BNODES * C1 / 4; t += AGG_T) {
            float4 v = make_float4(0.f, 0.f, 0.f, 0.f);
            if (node0 + (t >> 2) < n) v = ((const float4*)h)[(size_t)node0 * 4 + t];
            ((float4*)&h_s[0][0])[t] = v;
        }
    }
    __syncthreads();

    int base = b * CAP;
    int len = gcur[b] - base;
    if (len < 0) len = 0;
    if (len > CAP) len = CAP;
    const int* bp = barr + base;
    unsigned un = (unsigned)n;
    int chb = (tid & 1) << 3;
    int tb  = (tid & 1) << 2;

    GATHER_SCATTER(hu)
    __syncthreads();

    // finalize: de-bias (deg+1 incl. self), unscale, *inv -> accf
    const unsigned* au = (const unsigned*)&acc[0][0];
    for (int t = tid; t < BNODES * C1; t += AGG_T) {
        int loc = t >> 4, ch = t & 15;
        int node = (b << LOCB) + loc;
        float v = 0.f;
        if (node < n) {
            int dg = deg[node];
            unsigned wd = au[loc * (2 * ACC2P) + ch];
            int tot = (int)(wd + hu[(node << 4) + ch] - ((unsigned)(dg + 1) << BSH));
            v = (float)tot * INVFX * rsqrtf((float)(dg + 1));
        }
        accf[loc][ch] = v;
    }
    __syncthreads();

    // 16->64 matmuls: weights hoisted to registers, acc/h_s broadcast reads
    int och = tid & 63, g = tid >> 6;      // 8 groups x 16 locs
    float w1r[C1], w2r[C1];
    #pragma unroll
    for (int k = 0; k < C1; ++k) { w1r[k] = Wc[k][och]; w2r[k] = Wc[k][och + 64]; }
    float bb = b2[och], tb2 = t2b[och];
    for (int q = 0; q < 16; ++q) {
        int loc = (g << 4) + q;
        int node2 = (b << LOCB) + loc;
        if (node2 >= n) continue;
        float s1 = bb, s2 = tb2;
        #pragma unroll
        for (int k = 0; k < C1; ++k) {
            s1 += accf[loc][k] * w1r[k];
            s2 += h_s[loc][k]  * w2r[k];
        }
        out[(size_t)node2 * C2 + och] = fmaxf(s1, 0.f) + s2;
    }
}

extern "C" void kernel_launch(void* const* d_in, const int* in_sizes, int n_in,
                              void* d_out, int out_size, void* d_ws, size_t ws_size,
                              hipStream_t stream) {
    const float* x   = (const float*)d_in[0];
    const int*   ei  = (const int*)d_in[1];
    const float* W1  = (const float*)d_in[2];
    const float* b1  = (const float*)d_in[3];
    const float* W2  = (const float*)d_in[4];
    const float* b2  = (const float*)d_in[5];
    const float* T1  = (const float*)d_in[6];
    const float* t1b = (const float*)d_in[7];
    const float* T2  = (const float*)d_in[8];
    const float* t2b = (const float*)d_in[9];
    float* out = (float*)d_out;

    const int n = in_sizes[0] / INCH;       // 100000
    const int e = in_sizes[1] / 2;          // 3200000
    const int* row = ei;
    const int* col = ei + e;
    const int K = (n + BNODES - 1) >> LOCB; // 782 buckets

    // workspace layout
    char* ws = (char*)d_ws;
    int*      gcur = (int*)ws;                        ws += 4096;
    int*      deg  = (int*)ws;                        ws += (size_t)n * 4;
    float*    xT1  = (float*)ws;                      ws += (size_t)n * C1 * 4;
    float*    h    = (float*)ws;                      ws += (size_t)n * C1 * 4;
    unsigned* xW1u = (unsigned*)ws;                   ws += (size_t)n * C1 * 4; // 6.4 MB
    unsigned* hu   = (unsigned*)ws;                   ws += (size_t)n * C1 * 4; // 6.4 MB
    int*      barr = (int*)ws;                        ws += (size_t)K * CAP * 4; // 25.6 MB

    const int nbb = 390;     // bucket_kernel blocks

    binit_kernel  <<<(n + 255) / 256, 256, 0, stream>>>(gcur, K, deg, n);
    bucket_kernel <<<nbb, BKT_T, 0, stream>>>(row, col, gcur, barr, deg, e, n, K, nbb);

    linear1_kernel <<<(n + 15) / 16, 256, 0, stream>>>(x, W1, T1, t1b, deg, xW1u, xT1, n);
    agg1_bucket_kernel<<<K, AGG_T, 0, stream>>>(barr, gcur, deg, xW1u, xT1, b1, h, hu, n);
    agg2_bucket_kernel<<<K, AGG_T, 0, stream>>>(barr, gcur, deg, hu, h,
                                                W2, T2, b2, t2b, out, n);
}

// Round 11
// 268.852 us; speedup vs baseline: 1.3865x; 1.3865x over previous
//
#include <hip/hip_runtime.h>

#define INCH 128
#define C1   16
#define C2   64
#define LOCB 7                   // log2(nodes per bucket)
#define BNODES (1 << LOCB)       // 128 nodes per bucket
#define CAP  8192                // padded edge capacity per bucket
#define ROWBITS 17
#define ROWMASK ((1 << ROWBITS) - 1)
#define SENT 0xFFFFFFFFu         // sentinel: src field = 0x1FFFF >= n -> filtered
#define ACC2P 9                  // u64 acc row stride (odd -> bank-pair spread)
#define FXS   16384.0f           // 2^14 fixed-point scale
#define INVFX 6.103515625e-05f   // 2^-14
#define FXBH  524288.5f          // 2^19 bias + 0.5 (round-half-up via trunc)
#define BSH   19                 // bias shift for de-biasing
#define BKT_T 1024               // bucket_kernel threads
#define AGG_T 512                // agg/degree threads

typedef int iv4 __attribute__((ext_vector_type(4)));
typedef unsigned long long ulv2 __attribute__((ext_vector_type(2)));

// ---------------- binit: gcur[b] = b*CAP -----------------------------------
__global__ void binit_kernel(int* __restrict__ gcur, int K) {
    int t = blockIdx.x * blockDim.x + threadIdx.x;
    if (t < K) gcur[t] = t * CAP;
}

// ---------------- bucket edges, line-aligned padded reservations -----------
// r8-verified version: NO global deg atomics (r10 showed 3.2M random-address
// global RMWs triple this kernel: 40->153us, WRITE 77->130MB).
__global__ __launch_bounds__(BKT_T) void bucket_kernel(
    const int* __restrict__ row, const int* __restrict__ col,
    int* __restrict__ gcur, int* __restrict__ barr,
    int e, int n, int K, int nblocks)
{
    __shared__ int cnt[1024];     // valid count per bucket
    __shared__ int cur[1024];     // write cursor
    __shared__ int sst[1024];     // chunk start
    int tid = threadIdx.x;
    int e4 = e >> 2;
    long b0 = (long)blockIdx.x * e4 / nblocks;
    long b1 = (long)(blockIdx.x + 1) * e4 / nblocks;
    const iv4* c4p = (const iv4*)col;
    const iv4* r4p = (const iv4*)row;
    cnt[tid] = 0;
    __syncthreads();
    for (long i = b0 + tid; i < b1; i += BKT_T) {
        iv4 c4 = c4p[i], r4 = r4p[i];
        #pragma unroll
        for (int k = 0; k < 4; ++k) {
            unsigned c = (unsigned)c4[k], r = (unsigned)r4[k];
            if (c < (unsigned)n && r < (unsigned)n)
                atomicAdd(&cnt[c >> LOCB], 1);
        }
    }
    if (blockIdx.x == 0) {
        for (int i = e4 * 4 + tid; i < e; i += BKT_T) {
            unsigned c = (unsigned)col[i], r = (unsigned)row[i];
            if (c < (unsigned)n && r < (unsigned)n)
                atomicAdd(&cnt[c >> LOCB], 1);
        }
    }
    __syncthreads();
    if (tid < K) {
        int c = cnt[tid];
        int start = c ? atomicAdd(&gcur[tid], (c + 15) & ~15) : 0;
        cur[tid] = start;
        sst[tid] = start;
    }
    __syncthreads();
    for (long i = b0 + tid; i < b1; i += BKT_T) {
        iv4 c4 = c4p[i], r4 = r4p[i];
        #pragma unroll
        for (int k = 0; k < 4; ++k) {
            unsigned c = (unsigned)c4[k], r = (unsigned)r4[k];
            if (c < (unsigned)n && r < (unsigned)n) {
                int b = c >> LOCB;
                int slot = atomicAdd(&cur[b], 1);          // LDS int atomic
                if ((unsigned)slot < (unsigned)((b + 1) * CAP))
                    barr[slot] = (int)(r | ((c & (BNODES - 1)) << ROWBITS));
            }
        }
    }
    if (blockIdx.x == 0) {
        for (int i = e4 * 4 + tid; i < e; i += BKT_T) {
            unsigned c = (unsigned)col[i], r = (unsigned)row[i];
            if (c < (unsigned)n && r < (unsigned)n) {
                int b = c >> LOCB;
                int slot = atomicAdd(&cur[b], 1);
                if ((unsigned)slot < (unsigned)((b + 1) * CAP))
                    barr[slot] = (int)(r | ((c & (BNODES - 1)) << ROWBITS));
            }
        }
    }
    __syncthreads();
    // sentinel-fill the pad so every reserved line is fully written
    if (tid < K) {
        int c = cnt[tid];
        if (c) {
            int start = sst[tid];
            int end = start + c;
            int re  = start + ((c + 15) & ~15);
            int lim = (tid + 1) * CAP;
            if (end > lim) end = lim;
            if (re  > lim) re  = lim;
            for (int j = end; j < re; ++j) barr[j] = (int)SENT;
        }
    }
}

// ---------------- degree: per-bucket LDS histogram -> deg[] ----------------
__global__ __launch_bounds__(AGG_T) void degree_kernel(
    const int* __restrict__ barr, const int* __restrict__ gcur,
    int* __restrict__ deg, int n)
{
    __shared__ int lcnt[BNODES];
    int b = blockIdx.x, tid = threadIdx.x;
    if (tid < BNODES) lcnt[tid] = 0;
    __syncthreads();
    int base = b * CAP;
    int len = gcur[b] - base;
    if (len < 0) len = 0;
    if (len > CAP) len = CAP;
    int len4 = len >> 2;
    const iv4* b4 = (const iv4*)(barr + base);
    for (int i = tid; i < len4; i += AGG_T) {
        iv4 p4 = b4[i];
        #pragma unroll
        for (int k = 0; k < 4; ++k) {
            unsigned pk = (unsigned)p4[k];
            if ((pk & ROWMASK) < (unsigned)n)
                atomicAdd(&lcnt[(pk >> ROWBITS) & (BNODES - 1)], 1);
        }
    }
    __syncthreads();
    if (tid < BNODES) {
        int node = (b << LOCB) + tid;
        if (node < n) deg[node] = lcnt[tid];
    }
}

// ---------------- linear1: xW1u = u32 fixed-point((x@W1)*inv*2^14 + bias) --
__global__ __launch_bounds__(256) void linear1_kernel(
    const float* __restrict__ x, const float* __restrict__ W1,
    const float* __restrict__ T1, const float* __restrict__ t1b,
    const int* __restrict__ deg,
    unsigned* __restrict__ xW1u, float* __restrict__ xT1, int n)
{
    __shared__ float Wc[INCH][32];        // [:,0:16]=W1, [:,16:32]=t1_W
    __shared__ float xs[16][INCH + 4];
    int tid = threadIdx.x;

    for (int i = tid; i < INCH * C1; i += 256) {
        int k = i / C1, c = i % C1;
        Wc[k][c]      = W1[i];
        Wc[k][c + 16] = T1[i];
    }
    int node0 = blockIdx.x * 16;
    for (int i = tid; i < 16 * (INCH / 4); i += 256) {
        int r = i / (INCH / 4);
        int cc = i % (INCH / 4);
        int node = node0 + r;
        float4 v = make_float4(0.f, 0.f, 0.f, 0.f);
        if (node < n) v = ((const float4*)x)[(size_t)node * (INCH / 4) + cc];
        ((float4*)&xs[r][0])[cc] = v;
    }
    __syncthreads();

    int ch = tid & 15, nl = tid >> 4;
    int node = node0 + nl;
    if (node >= n) return;
    float a1 = 0.f, a2 = 0.f;
    #pragma unroll
    for (int k = 0; k < INCH; ++k) {
        float xv = xs[nl][k];
        a1 += xv * Wc[k][ch];
        a2 += xv * Wc[k][ch + 16];
    }
    float ic = rsqrtf((float)(deg[node] + 1));
    // pre-scaled by inv[src]*2^14, pre-biased by 2^19: atomic-ready integer
    xW1u[(node << 4) + ch] = (unsigned)(a1 * ic * FXS + FXBH);
    xT1[(node << 4) + ch]  = a2 + t1b[ch];
}

// ---- per-edge scatter: values are PRE-PACKED u32 pairs -> load 2x dwordx4
//      as 4 u64 words, feed ds_add_u64 directly. Zero per-edge pack VALU.
#define EDGE_GS(PK, GA, GB)                                                   \
    do {                                                                      \
        if (((PK) & ROWMASK) < un) {                                          \
            unsigned long long* _a = &acc[(((PK) >> ROWBITS) & (BNODES - 1))][tb]; \
            atomicAdd(&_a[0], (GA)[0]);                                       \
            atomicAdd(&_a[1], (GA)[1]);                                       \
            atomicAdd(&_a[2], (GB)[0]);                                       \
            atomicAdd(&_a[3], (GB)[1]);                                       \
        }                                                                     \
    } while (0)

#define GATHER_SCATTER(SRCBUF)                                                \
    {                                                                         \
        int jj = tid >> 1;                                                    \
        for (int i0 = jj * 4; i0 + 3 < len; i0 += (AGG_T * 2)) {              \
            iv4 w = *(const iv4*)(bp + i0);                                   \
            unsigned s0 = (unsigned)w[0] & ROWMASK, s1 = (unsigned)w[1] & ROWMASK; \
            unsigned s2 = (unsigned)w[2] & ROWMASK, s3 = (unsigned)w[3] & ROWMASK; \
            unsigned c0 = s0 < un ? s0 : 0u, c1 = s1 < un ? s1 : 0u;          \
            unsigned c2 = s2 < un ? s2 : 0u, c3 = s3 < un ? s3 : 0u;          \
            const ulv2* p0 = (const ulv2*)(SRCBUF + ((size_t)c0 << 4) + chb); \
            const ulv2* p1 = (const ulv2*)(SRCBUF + ((size_t)c1 << 4) + chb); \
            const ulv2* p2 = (const ulv2*)(SRCBUF + ((size_t)c2 << 4) + chb); \
            const ulv2* p3 = (const ulv2*)(SRCBUF + ((size_t)c3 << 4) + chb); \
            ulv2 ga0 = p0[0], gb0 = p0[1];                                    \
            ulv2 ga1 = p1[0], gb1 = p1[1];                                    \
            ulv2 ga2 = p2[0], gb2 = p2[1];                                    \
            ulv2 ga3 = p3[0], gb3 = p3[1];                                    \
            EDGE_GS((unsigned)w[0], ga0, gb0);                                \
            EDGE_GS((unsigned)w[1], ga1, gb1);                                \
            EDGE_GS((unsigned)w[2], ga2, gb2);                                \
            EDGE_GS((unsigned)w[3], ga3, gb3);                                \
        }                                                                     \
    }

// ---------------- agg1: bucket u64-LDS accumulate + fused epilogue1 --------
__global__ __launch_bounds__(AGG_T) void agg1_bucket_kernel(
    const int* __restrict__ barr, const int* __restrict__ gcur,
    const int* __restrict__ deg, const unsigned* __restrict__ xW1u,
    const float* __restrict__ xT1, const float* __restrict__ b1,
    float* __restrict__ h, unsigned* __restrict__ hu, int n)
{
    __shared__ unsigned long long acc[BNODES][ACC2P];   // 9216 B
    int b = blockIdx.x, tid = threadIdx.x;
    for (int i = tid; i < BNODES * ACC2P; i += AGG_T) (&acc[0][0])[i] = 0ull;
    __syncthreads();

    int base = b * CAP;
    int len = gcur[b] - base;
    if (len < 0) len = 0;
    if (len > CAP) len = CAP;
    const int* bp = barr + base;
    unsigned un = (unsigned)n;
    int chb = (tid & 1) << 3;              // u32 channel base: 0 / 8
    int tb  = (tid & 1) << 2;              // u64 slot base: 0..3 / 4..7

    GATHER_SCATTER(xW1u)
    __syncthreads();

    // epilogue: de-bias (deg+1 biases incl. self), unscale, bias, relu
    const unsigned* au = (const unsigned*)&acc[0][0];
    for (int t = tid; t < BNODES * C1; t += AGG_T) {
        int loc = t >> 4, ch = t & 15;
        int node = (b << LOCB) + loc;
        if (node >= n) continue;
        int idx = (node << 4) + ch;
        int dg = deg[node];
        unsigned wd = au[loc * (2 * ACC2P) + ch];
        int tot = (int)(wd + xW1u[idx] - ((unsigned)(dg + 1) << BSH));
        float ic = rsqrtf((float)(dg + 1));
        float v = (float)tot * INVFX * ic + b1[ch];
        float hv = fmaxf(v, 0.f) + xT1[idx];
        h[idx]  = hv;
        hu[idx] = (unsigned)(hv * ic * FXS + FXBH);  // atomic-ready for layer 2
    }
}

// ---------------- agg2: bucket u64-LDS accumulate + fused 16->64 linears ---
__global__ __launch_bounds__(AGG_T) void agg2_bucket_kernel(
    const int* __restrict__ barr, const int* __restrict__ gcur,
    const int* __restrict__ deg, const unsigned* __restrict__ hu,
    const float* __restrict__ h,
    const float* __restrict__ W2, const float* __restrict__ T2,
    const float* __restrict__ b2, const float* __restrict__ t2b,
    float* __restrict__ out, int n)
{
    __shared__ unsigned long long acc[BNODES][ACC2P];   // 9216 B
    __shared__ float Wc[C1][128];          // 8 KB: [:,0:64]=W2, [:,64:128]=T2
    __shared__ float h_s[BNODES][C1];      // 8 KB: unscaled h for identity2
    __shared__ float accf[BNODES][C1 + 1]; // 8.7 KB: finalized aggregate
    int b = blockIdx.x, tid = threadIdx.x;
    for (int i = tid; i < BNODES * ACC2P; i += AGG_T) (&acc[0][0])[i] = 0ull;
    for (int i = tid; i < C1 * 128; i += AGG_T) {
        int k = i >> 7, c = i & 127;
        Wc[k][c] = (c < 64) ? W2[k * C2 + c] : T2[k * C2 + (c - 64)];
    }
    {   // stage h rows (contiguous across bucket -> coalesced float4)
        int node0 = b << LOCB;
        for (int t = tid; t < BNODES * C1 / 4; t += AGG_T) {
            float4 v = make_float4(0.f, 0.f, 0.f, 0.f);
            if (node0 + (t >> 2) < n) v = ((const float4*)h)[(size_t)node0 * 4 + t];
            ((float4*)&h_s[0][0])[t] = v;
        }
    }
    __syncthreads();

    int base = b * CAP;
    int len = gcur[b] - base;
    if (len < 0) len = 0;
    if (len > CAP) len = CAP;
    const int* bp = barr + base;
    unsigned un = (unsigned)n;
    int chb = (tid & 1) << 3;
    int tb  = (tid & 1) << 2;

    GATHER_SCATTER(hu)
    __syncthreads();

    // finalize: de-bias (deg+1 incl. self), unscale, *inv -> accf
    const unsigned* au = (const unsigned*)&acc[0][0];
    for (int t = tid; t < BNODES * C1; t += AGG_T) {
        int loc = t >> 4, ch = t & 15;
        int node = (b << LOCB) + loc;
        float v = 0.f;
        if (node < n) {
            int dg = deg[node];
            unsigned wd = au[loc * (2 * ACC2P) + ch];
            int tot = (int)(wd + hu[(node << 4) + ch] - ((unsigned)(dg + 1) << BSH));
            v = (float)tot * INVFX * rsqrtf((float)(dg + 1));
        }
        accf[loc][ch] = v;
    }
    __syncthreads();

    // 16->64 matmuls: weights hoisted to registers, acc/h_s broadcast reads
    int och = tid & 63, g = tid >> 6;      // 8 groups x 16 locs
    float w1r[C1], w2r[C1];
    #pragma unroll
    for (int k = 0; k < C1; ++k) { w1r[k] = Wc[k][och]; w2r[k] = Wc[k][och + 64]; }
    float bb = b2[och], tb2 = t2b[och];
    for (int q = 0; q < 16; ++q) {
        int loc = (g << 4) + q;
        int node2 = (b << LOCB) + loc;
        if (node2 >= n) continue;
        float s1 = bb, s2 = tb2;
        #pragma unroll
        for (int k = 0; k < C1; ++k) {
            s1 += accf[loc][k] * w1r[k];
            s2 += h_s[loc][k]  * w2r[k];
        }
        out[(size_t)node2 * C2 + och] = fmaxf(s1, 0.f) + s2;
    }
}

extern "C" void kernel_launch(void* const* d_in, const int* in_sizes, int n_in,
                              void* d_out, int out_size, void* d_ws, size_t ws_size,
                              hipStream_t stream) {
    const float* x   = (const float*)d_in[0];
    const int*   ei  = (const int*)d_in[1];
    const float* W1  = (const float*)d_in[2];
    const float* b1  = (const float*)d_in[3];
    const float* W2  = (const float*)d_in[4];
    const float* b2  = (const float*)d_in[5];
    const float* T1  = (const float*)d_in[6];
    const float* t1b = (const float*)d_in[7];
    const float* T2  = (const float*)d_in[8];
    const float* t2b = (const float*)d_in[9];
    float* out = (float*)d_out;

    const int n = in_sizes[0] / INCH;       // 100000
    const int e = in_sizes[1] / 2;          // 3200000
    const int* row = ei;
    const int* col = ei + e;
    const int K = (n + BNODES - 1) >> LOCB; // 782 buckets

    // workspace layout
    char* ws = (char*)d_ws;
    int*      gcur = (int*)ws;                        ws += 4096;
    int*      deg  = (int*)ws;                        ws += (size_t)n * 4;
    float*    xT1  = (float*)ws;                      ws += (size_t)n * C1 * 4;
    float*    h    = (float*)ws;                      ws += (size_t)n * C1 * 4;
    unsigned* xW1u = (unsigned*)ws;                   ws += (size_t)n * C1 * 4; // 6.4 MB
    unsigned* hu   = (unsigned*)ws;                   ws += (size_t)n * C1 * 4; // 6.4 MB
    int*      barr = (int*)ws;                        ws += (size_t)K * CAP * 4; // 25.6 MB

    const int nbb = 390;     // bucket_kernel blocks

    binit_kernel  <<<(K + 255) / 256, 256, 0, stream>>>(gcur, K);
    bucket_kernel <<<nbb, BKT_T, 0, stream>>>(row, col, gcur, barr, e, n, K, nbb);
    degree_kernel <<<K, AGG_T, 0, stream>>>(barr, gcur, deg, n);

    linear1_kernel <<<(n + 15) / 16, 256, 0, stream>>>(x, W1, T1, t1b, deg, xW1u, xT1, n);
    agg1_bucket_kernel<<<K, AGG_T, 0, stream>>>(barr, gcur, deg, xW1u, xT1, b1, h, hu, n);
    agg2_bucket_kernel<<<K, AGG_T, 0, stream>>>(barr, gcur, deg, hu, h,
                                                W2, T2, b2, t2b, out, n);
}

// Round 12
// 250.888 us; speedup vs baseline: 1.4858x; 1.0716x over previous
//
#include <hip/hip_runtime.h>

#define INCH 128
#define C1   16
#define C2   64
#define LOCB 7                   // log2(nodes per bucket)
#define BNODES (1 << LOCB)       // 128 nodes per bucket
#define CAP  8192                // padded edge capacity per bucket
#define ROWBITS 17
#define ROWMASK ((1 << ROWBITS) - 1)
#define SENT 0xFFFFFFFFu         // sentinel: src field = 0x1FFFF >= n -> filtered
#define ACC2P 9                  // u64 acc row stride (odd -> bank-pair spread)
#define FXS   512.0f             // 2^9 fixed-point scale (u16 payload)
#define INVFX 0.001953125f       // 2^-9
#define U16B  32768.5f           // 2^15 bias + 0.5 (round-half-up via trunc)
#define BSH   15                 // bias shift for de-biasing
#define BKT_T 1024               // bucket_kernel threads
#define AGG_T 512                // agg/degree threads

typedef int iv4 __attribute__((ext_vector_type(4)));

// ---------------- binit: gcur[b] = b*CAP -----------------------------------
__global__ void binit_kernel(int* __restrict__ gcur, int K) {
    int t = blockIdx.x * blockDim.x + threadIdx.x;
    if (t < K) gcur[t] = t * CAP;
}

// ---------------- bucket edges, line-aligned padded reservations -----------
// r8-verified: no global per-edge RMWs (r5/r10 lessons), 1024 threads (r7).
__global__ __launch_bounds__(BKT_T) void bucket_kernel(
    const int* __restrict__ row, const int* __restrict__ col,
    int* __restrict__ gcur, int* __restrict__ barr,
    int e, int n, int K, int nblocks)
{
    __shared__ int cnt[1024];     // valid count per bucket
    __shared__ int cur[1024];     // write cursor
    __shared__ int sst[1024];     // chunk start
    int tid = threadIdx.x;
    int e4 = e >> 2;
    long b0 = (long)blockIdx.x * e4 / nblocks;
    long b1 = (long)(blockIdx.x + 1) * e4 / nblocks;
    const iv4* c4p = (const iv4*)col;
    const iv4* r4p = (const iv4*)row;
    cnt[tid] = 0;
    __syncthreads();
    for (long i = b0 + tid; i < b1; i += BKT_T) {
        iv4 c4 = c4p[i], r4 = r4p[i];
        #pragma unroll
        for (int k = 0; k < 4; ++k) {
            unsigned c = (unsigned)c4[k], r = (unsigned)r4[k];
            if (c < (unsigned)n && r < (unsigned)n)
                atomicAdd(&cnt[c >> LOCB], 1);
        }
    }
    if (blockIdx.x == 0) {
        for (int i = e4 * 4 + tid; i < e; i += BKT_T) {
            unsigned c = (unsigned)col[i], r = (unsigned)row[i];
            if (c < (unsigned)n && r < (unsigned)n)
                atomicAdd(&cnt[c >> LOCB], 1);
        }
    }
    __syncthreads();
    if (tid < K) {
        int c = cnt[tid];
        int start = c ? atomicAdd(&gcur[tid], (c + 15) & ~15) : 0;
        cur[tid] = start;
        sst[tid] = start;
    }
    __syncthreads();
    for (long i = b0 + tid; i < b1; i += BKT_T) {
        iv4 c4 = c4p[i], r4 = r4p[i];
        #pragma unroll
        for (int k = 0; k < 4; ++k) {
            unsigned c = (unsigned)c4[k], r = (unsigned)r4[k];
            if (c < (unsigned)n && r < (unsigned)n) {
                int b = c >> LOCB;
                int slot = atomicAdd(&cur[b], 1);          // LDS int atomic
                if ((unsigned)slot < (unsigned)((b + 1) * CAP))
                    barr[slot] = (int)(r | ((c & (BNODES - 1)) << ROWBITS));
            }
        }
    }
    if (blockIdx.x == 0) {
        for (int i = e4 * 4 + tid; i < e; i += BKT_T) {
            unsigned c = (unsigned)col[i], r = (unsigned)row[i];
            if (c < (unsigned)n && r < (unsigned)n) {
                int b = c >> LOCB;
                int slot = atomicAdd(&cur[b], 1);
                if ((unsigned)slot < (unsigned)((b + 1) * CAP))
                    barr[slot] = (int)(r | ((c & (BNODES - 1)) << ROWBITS));
            }
        }
    }
    __syncthreads();
    // sentinel-fill the pad so every reserved line is fully written
    if (tid < K) {
        int c = cnt[tid];
        if (c) {
            int start = sst[tid];
            int end = start + c;
            int re  = start + ((c + 15) & ~15);
            int lim = (tid + 1) * CAP;
            if (end > lim) end = lim;
            if (re  > lim) re  = lim;
            for (int j = end; j < re; ++j) barr[j] = (int)SENT;
        }
    }
}

// ---------------- degree: per-bucket LDS histogram -> deg[] ----------------
__global__ __launch_bounds__(AGG_T) void degree_kernel(
    const int* __restrict__ barr, const int* __restrict__ gcur,
    int* __restrict__ deg, int n)
{
    __shared__ int lcnt[BNODES];
    int b = blockIdx.x, tid = threadIdx.x;
    if (tid < BNODES) lcnt[tid] = 0;
    __syncthreads();
    int base = b * CAP;
    int len = gcur[b] - base;
    if (len < 0) len = 0;
    if (len > CAP) len = CAP;
    int len4 = len >> 2;
    const iv4* b4 = (const iv4*)(barr + base);
    for (int i = tid; i < len4; i += AGG_T) {
        iv4 p4 = b4[i];
        #pragma unroll
        for (int k = 0; k < 4; ++k) {
            unsigned pk = (unsigned)p4[k];
            if ((pk & ROWMASK) < (unsigned)n)
                atomicAdd(&lcnt[(pk >> ROWBITS) & (BNODES - 1)], 1);
        }
    }
    __syncthreads();
    if (tid < BNODES) {
        int node = (b << LOCB) + tid;
        if (node < n) deg[node] = lcnt[tid];
    }
}

// ---- u16 staging encode: clamp, scale 2^9, bias 2^15, round ---------------
__device__ __forceinline__ unsigned short enc16(float v) {
    float c = fminf(fmaxf(v, -63.0f), 63.0f);
    return (unsigned short)(c * FXS + U16B);
}

// ---------------- linear1: xu16 = enc16((x@W1)*inv), xT1 = x@t1_W + t1_b ---
__global__ __launch_bounds__(256) void linear1_kernel(
    const float* __restrict__ x, const float* __restrict__ W1,
    const float* __restrict__ T1, const float* __restrict__ t1b,
    const int* __restrict__ deg,
    unsigned short* __restrict__ xu16, float* __restrict__ xT1, int n)
{
    __shared__ float Wc[INCH][32];        // [:,0:16]=W1, [:,16:32]=t1_W
    __shared__ float xs[16][INCH + 4];
    int tid = threadIdx.x;

    for (int i = tid; i < INCH * C1; i += 256) {
        int k = i / C1, c = i % C1;
        Wc[k][c]      = W1[i];
        Wc[k][c + 16] = T1[i];
    }
    int node0 = blockIdx.x * 16;
    for (int i = tid; i < 16 * (INCH / 4); i += 256) {
        int r = i / (INCH / 4);
        int cc = i % (INCH / 4);
        int node = node0 + r;
        float4 v = make_float4(0.f, 0.f, 0.f, 0.f);
        if (node < n) v = ((const float4*)x)[(size_t)node * (INCH / 4) + cc];
        ((float4*)&xs[r][0])[cc] = v;
    }
    __syncthreads();

    int ch = tid & 15, nl = tid >> 4;
    int node = node0 + nl;
    if (node >= n) return;
    float a1 = 0.f, a2 = 0.f;
    #pragma unroll
    for (int k = 0; k < INCH; ++k) {
        float xv = xs[nl][k];
        a1 += xv * Wc[k][ch];
        a2 += xv * Wc[k][ch + 16];
    }
    float ic = rsqrtf((float)(deg[node] + 1));
    xu16[(node << 4) + ch] = enc16(a1 * ic);   // pre-scaled, biased, atomic-ready
    xT1[(node << 4) + ch]  = a2 + t1b[ch];
}

// ---- per-edge scatter: each loaded dword = (ch_even | ch_odd<<16), both
//      pre-biased u16 -> unpack with 2 int ops into a u64 for ds_add_u64.
#define EDGE_GS(PK, G)                                                        \
    do {                                                                      \
        if (((PK) & ROWMASK) < un) {                                          \
            unsigned long long* _a = &acc[(((PK) >> ROWBITS) & (BNODES - 1))][tb]; \
            _Pragma("unroll")                                                 \
            for (int _j = 0; _j < 4; ++_j) {                                  \
                unsigned _d = (unsigned)(G)[_j];                              \
                atomicAdd(&_a[_j],                                            \
                    ((unsigned long long)(_d >> 16) << 32) | (_d & 0xFFFFu)); \
            }                                                                 \
        }                                                                     \
    } while (0)

// ---- gather+scatter core: 2 lanes/edge-quad-half; lane loads 4 consecutive
//      barr words (dwordx4), 4 ushort8 (iv4) gathers, 16 ds_add_u64/4 edges.
#define GATHER_SCATTER(TBL)                                                   \
    {                                                                         \
        int jj = tid >> 1;                                                    \
        for (int i0 = jj * 4; i0 + 3 < len; i0 += (AGG_T * 2)) {              \
            iv4 w = *(const iv4*)(bp + i0);                                   \
            unsigned s0 = (unsigned)w[0] & ROWMASK, s1 = (unsigned)w[1] & ROWMASK; \
            unsigned s2 = (unsigned)w[2] & ROWMASK, s3 = (unsigned)w[3] & ROWMASK; \
            unsigned c0 = s0 < un ? s0 : 0u, c1 = s1 < un ? s1 : 0u;          \
            unsigned c2 = s2 < un ? s2 : 0u, c3 = s3 < un ? s3 : 0u;          \
            iv4 g0 = *(const iv4*)(TBL + ((size_t)c0 << 3) + tb4);            \
            iv4 g1 = *(const iv4*)(TBL + ((size_t)c1 << 3) + tb4);            \
            iv4 g2 = *(const iv4*)(TBL + ((size_t)c2 << 3) + tb4);            \
            iv4 g3 = *(const iv4*)(TBL + ((size_t)c3 << 3) + tb4);            \
            EDGE_GS((unsigned)w[0], g0);                                      \
            EDGE_GS((unsigned)w[1], g1);                                      \
            EDGE_GS((unsigned)w[2], g2);                                      \
            EDGE_GS((unsigned)w[3], g3);                                      \
        }                                                                     \
    }

// ---------------- agg1: bucket u64-LDS accumulate + fused epilogue1 --------
__global__ __launch_bounds__(AGG_T) void agg1_bucket_kernel(
    const int* __restrict__ barr, const int* __restrict__ gcur,
    const int* __restrict__ deg, const unsigned short* __restrict__ xu16,
    const float* __restrict__ xT1, const float* __restrict__ b1,
    float* __restrict__ h, unsigned short* __restrict__ hu16, int n)
{
    __shared__ unsigned long long acc[BNODES][ACC2P];   // 9216 B
    int b = blockIdx.x, tid = threadIdx.x;
    for (int i = tid; i < BNODES * ACC2P; i += AGG_T) (&acc[0][0])[i] = 0ull;
    __syncthreads();

    int base = b * CAP;
    int len = gcur[b] - base;
    if (len < 0) len = 0;
    if (len > CAP) len = CAP;
    const int* bp = barr + base;
    const unsigned* tblw = (const unsigned*)xu16;   // dword view: node*8 + j
    unsigned un = (unsigned)n;
    int tb4 = (tid & 1) << 2;              // dword base within row: 0 / 4
    int tb  = (tid & 1) << 2;              // u64 slot base: 0..3 / 4..7

    GATHER_SCATTER(tblw)
    __syncthreads();

    // epilogue: de-bias ((deg+1)<<15 incl. self), unscale, bias, relu
    const unsigned* au = (const unsigned*)&acc[0][0];
    for (int t = tid; t < BNODES * C1; t += AGG_T) {
        int loc = t >> 4, ch = t & 15;
        int node = (b << LOCB) + loc;
        if (node >= n) continue;
        int idx = (node << 4) + ch;
        int dg = deg[node];
        unsigned wd = au[loc * (2 * ACC2P) + ch];
        int tot = (int)(wd + xu16[idx] - ((unsigned)(dg + 1) << BSH));
        float ic = rsqrtf((float)(dg + 1));
        float v = (float)tot * INVFX * ic + b1[ch];
        float hv = fmaxf(v, 0.f) + xT1[idx];
        h[idx]    = hv;
        hu16[idx] = enc16(hv * ic);        // atomic-ready for layer 2
    }
}

// ---------------- agg2: bucket u64-LDS accumulate + fused 16->64 linears ---
__global__ __launch_bounds__(AGG_T) void agg2_bucket_kernel(
    const int* __restrict__ barr, const int* __restrict__ gcur,
    const int* __restrict__ deg, const unsigned short* __restrict__ hu16,
    const float* __restrict__ h,
    const float* __restrict__ W2, const float* __restrict__ T2,
    const float* __restrict__ b2, const float* __restrict__ t2b,
    float* __restrict__ out, int n)
{
    __shared__ unsigned long long acc[BNODES][ACC2P];   // 9216 B
    __shared__ float Wc[C1][128];          // 8 KB: [:,0:64]=W2, [:,64:128]=T2
    __shared__ float h_s[BNODES][C1];      // 8 KB: unscaled h for identity2
    __shared__ float accf[BNODES][C1 + 1]; // 8.7 KB: finalized aggregate
    int b = blockIdx.x, tid = threadIdx.x;
    for (int i = tid; i < BNODES * ACC2P; i += AGG_T) (&acc[0][0])[i] = 0ull;
    for (int i = tid; i < C1 * 128; i += AGG_T) {
        int k = i >> 7, c = i & 127;
        Wc[k][c] = (c < 64) ? W2[k * C2 + c] : T2[k * C2 + (c - 64)];
    }
    {   // stage h rows (contiguous across bucket -> coalesced float4)
        int node0 = b << LOCB;
        for (int t = tid; t < BNODES * C1 / 4; t += AGG_T) {
            float4 v = make_float4(0.f, 0.f, 0.f, 0.f);
            if (node0 + (t >> 2) < n) v = ((const float4*)h)[(size_t)node0 * 4 + t];
            ((float4*)&h_s[0][0])[t] = v;
        }
    }
    __syncthreads();

    int base = b * CAP;
    int len = gcur[b] - base;
    if (len < 0) len = 0;
    if (len > CAP) len = CAP;
    const int* bp = barr + base;
    const unsigned* tblw = (const unsigned*)hu16;
    unsigned un = (unsigned)n;
    int tb4 = (tid & 1) << 2;
    int tb  = (tid & 1) << 2;

    GATHER_SCATTER(tblw)
    __syncthreads();

    // finalize: de-bias ((deg+1)<<15 incl. self), unscale, *inv -> accf
    const unsigned* au = (const unsigned*)&acc[0][0];
    for (int t = tid; t < BNODES * C1; t += AGG_T) {
        int loc = t >> 4, ch = t & 15;
        int node = (b << LOCB) + loc;
        float v = 0.f;
        if (node < n) {
            int dg = deg[node];
            unsigned wd = au[loc * (2 * ACC2P) + ch];
            int tot = (int)(wd + hu16[(node << 4) + ch] - ((unsigned)(dg + 1) << BSH));
            v = (float)tot * INVFX * rsqrtf((float)(dg + 1));
        }
        accf[loc][ch] = v;
    }
    __syncthreads();

    // 16->64 matmuls: weights hoisted to registers, acc/h_s broadcast reads
    int och = tid & 63, g = tid >> 6;      // 8 groups x 16 locs
    float w1r[C1], w2r[C1];
    #pragma unroll
    for (int k = 0; k < C1; ++k) { w1r[k] = Wc[k][och]; w2r[k] = Wc[k][och + 64]; }
    float bb = b2[och], tb2 = t2b[och];
    for (int q = 0; q < 16; ++q) {
        int loc = (g << 4) + q;
        int node2 = (b << LOCB) + loc;
        if (node2 >= n) continue;
        float s1 = bb, s2 = tb2;
        #pragma unroll
        for (int k = 0; k < C1; ++k) {
            s1 += accf[loc][k] * w1r[k];
            s2 += h_s[loc][k]  * w2r[k];
        }
        out[(size_t)node2 * C2 + och] = fmaxf(s1, 0.f) + s2;
    }
}

extern "C" void kernel_launch(void* const* d_in, const int* in_sizes, int n_in,
                              void* d_out, int out_size, void* d_ws, size_t ws_size,
                              hipStream_t stream) {
    const float* x   = (const float*)d_in[0];
    const int*   ei  = (const int*)d_in[1];
    const float* W1  = (const float*)d_in[2];
    const float* b1  = (const float*)d_in[3];
    const float* W2  = (const float*)d_in[4];
    const float* b2  = (const float*)d_in[5];
    const float* T1  = (const float*)d_in[6];
    const float* t1b = (const float*)d_in[7];
    const float* T2  = (const float*)d_in[8];
    const float* t2b = (const float*)d_in[9];
    float* out = (float*)d_out;

    const int n = in_sizes[0] / INCH;       // 100000
    const int e = in_sizes[1] / 2;          // 3200000
    const int* row = ei;
    const int* col = ei + e;
    const int K = (n + BNODES - 1) >> LOCB; // 782 buckets

    // workspace layout
    char* ws = (char*)d_ws;
    int*            gcur = (int*)ws;                  ws += 4096;
    int*            deg  = (int*)ws;                  ws += (size_t)n * 4;
    float*          xT1  = (float*)ws;                ws += (size_t)n * C1 * 4;
    float*          h    = (float*)ws;                ws += (size_t)n * C1 * 4;
    unsigned short* xu16 = (unsigned short*)ws;       ws += (size_t)n * C1 * 2; // 3.2 MB (L2-resident)
    unsigned short* hu16 = (unsigned short*)ws;       ws += (size_t)n * C1 * 2; // 3.2 MB
    int*            barr = (int*)ws;                  ws += (size_t)K * CAP * 4; // 25.6 MB

    const int nbb = 390;     // bucket_kernel blocks

    binit_kernel  <<<(K + 255) / 256, 256, 0, stream>>>(gcur, K);
    bucket_kernel <<<nbb, BKT_T, 0, stream>>>(row, col, gcur, barr, e, n, K, nbb);
    degree_kernel <<<K, AGG_T, 0, stream>>>(barr, gcur, deg, n);

    linear1_kernel <<<(n + 15) / 16, 256, 0, stream>>>(x, W1, T1, t1b, deg, xu16, xT1, n);
    agg1_bucket_kernel<<<K, AGG_T, 0, stream>>>(barr, gcur, deg, xu16, xT1, b1, h, hu16, n);
    agg2_bucket_kernel<<<K, AGG_T, 0, stream>>>(barr, gcur, deg, hu16, h,
                                                W2, T2, b2, t2b, out, n);
}